// Round 17
// baseline (70.901 us; speedup 1.0000x reference)
//
#include <hip/hip_runtime.h>
#include <hip/hip_bf16.h>

typedef __attribute__((ext_vector_type(8))) short bf16x8;
typedef __attribute__((ext_vector_type(4))) float f32x4;
typedef __attribute__((ext_vector_type(4))) unsigned int u32x4;
typedef unsigned short u16;
typedef unsigned int u32;

static constexpr int KDIM  = 784;   // 28*28
static constexpr int KP    = 800;   // K padded (weff zero-pads k>=784 and n>=300)
static constexpr int NDIM  = 300;
static constexpr int NP    = 320;
static constexpr int DDIM  = 10;
static constexpr int BM    = 256;   // rows per block -> grid = 256 = 1 block/CU
static constexpr int BK    = 32;
static constexpr int NSTEP = 25;
static constexpr int H1STR = 328;
static constexpr int NROW  = 65536;
static constexpr int NTHR  = 512;   // 8 waves: 2m x 4n
// LDS bytes: A fp32 3 x 32768 @ 0; B bf16 2 x 20480 @ 98304. Total 139264.
static constexpr int ABYTES = 32768;
static constexpr int BBYTES = 20480;
static constexpr int BBASE  = 98304;

__device__ __forceinline__ u16 f2bf(float f) {
  unsigned u = __builtin_bit_cast(unsigned, f);
  u += 0x7fffu + ((u >> 16) & 1u);   // RNE
  return (u16)(u >> 16);
}
__device__ __forceinline__ u32 pk2(float a, float b) {
  u32 r;
  asm("v_cvt_pk_bf16_f32 %0, %1, %2" : "=v"(r) : "v"(a), "v"(b));
  return r;
}
__device__ __forceinline__ void gll16(const void* g, void* l) {
  __builtin_amdgcn_global_load_lds(
      (const __attribute__((address_space(1))) void*)g,
      (__attribute__((address_space(3))) void*)l, 16, 0, 0);
}

// ---- Kernel A: fold conv into first linear layer; weff_t[n][k] bf16, zero-padded ----
__global__ void build_weff(const float* __restrict__ cw,
                           const float* __restrict__ w1,
                           u16* __restrict__ weff) {
  int idx = blockIdx.x * 256 + threadIdx.x;
  if (idx >= NP * KP) return;
  int n = idx / KP;
  int k = idx - n * KP;
  float acc = 0.f;
  if (n < NDIM && k < KDIM) {
    int r = k / 28, c = k - (k / 28) * 28;
    #pragma unroll
    for (int dr = 0; dr < 3; ++dr) {
      int orr = r - dr;
      if ((unsigned)orr < 26u) {
        #pragma unroll
        for (int dc = 0; dc < 3; ++dc) {
          int oc = c - dc;
          if ((unsigned)oc < 26u)
            acc += cw[dr * 3 + dc] * w1[(orr * 26 + oc) * NDIM + n];
        }
      }
    }
  }
  weff[n * KP + k] = f2bf(acc);
}

// ---- Kernel B: out = relu(x @ Weff + b1) @ w2 + b2 ----
// r9 base (61.7us) with the K-step split into 4 phase-locked sub-phases
// (m201 8-phase pattern): per phase {ds_read this phase's A frags (+B/stage
// in p0/p1) -> s_barrier -> lgkmcnt(0) -> setprio(1) -> pk2+10 MFMA ->
// setprio(0) -> s_barrier}. One counted vmcnt(4) per step (end of p3) keeps
// A(t+2) in flight exactly as r9. Staging maps/buffers identical to r9.
__global__ void __launch_bounds__(NTHR, 2)
fused_mlp(const float* __restrict__ x, const float* __restrict__ b1,
          const float* __restrict__ w2, const float* __restrict__ b2,
          const u16* __restrict__ weff, float* __restrict__ out) {
  __shared__ __align__(16) u16 lds[69632];   // 139264 B -> 1 block/CU

  const int tid  = threadIdx.x;
  const int wv   = tid >> 6;
  const int lane = tid & 63;
  const int l16  = lane & 15;
  const int lhi  = lane >> 4;     // 0..3
  const int wm   = wv >> 2;       // 0..1 -> rows wm*128
  const int wn   = wv & 3;        // 0..3 -> cols wn*80
  const int bm   = blockIdx.x * BM;
  const int wvn  = wn * 80;

  // A staging (4 chunks/thread): slot s in [0,2048), row=s>>3 (8x16B/row),
  // global chunk qg = (s&7) ^ (row&7)  (line-coalesced + bank-even)
  int aRow[4], aQg[4];
  #pragma unroll
  for (int it = 0; it < 4; ++it) {
    int s = tid + it * NTHR;
    aRow[it] = s >> 3;
    aQg[it]  = (s & 7) ^ (aRow[it] & 7);
  }
  // B staging (3 chunks/thread, slots 1024..1279 written twice benignly)
  int bRow[3], bQg[3];
  #pragma unroll
  for (int i = 0; i < 3; ++i) {
    int s = (i < 2) ? (tid + i * NTHR) : (1024 + (tid & 255));
    bRow[i] = s >> 2;
    bQg[i]  = (s & 3) ^ (bRow[i] & 3);
  }

  auto stageA = [&](int bufi, int t) {
    char* base = (char*)lds + bufi * ABYTES;
    int k0 = (t < NSTEP) ? t * BK : 0;
    #pragma unroll
    for (int it = 0; it < 4; ++it) {
      int kof = k0 + aQg[it] * 4;
      if (kof >= KDIM) kof = aQg[it] * 4;   // tail: finite garbage, B zero-pad
      gll16(x + (size_t)(bm + aRow[it]) * KDIM + kof,
            base + (tid + it * NTHR) * 16);
    }
  };
  auto stageB = [&](int bufi, int t) {
    char* base = (char*)lds + BBASE + bufi * BBYTES;
    int k0 = (t < NSTEP) ? t * BK : 0;
    #pragma unroll
    for (int i = 0; i < 3; ++i) {
      int s = (i < 2) ? (tid + i * NTHR) : (1024 + (tid & 255));
      gll16(weff + (size_t)bRow[i] * KP + k0 + bQg[i] * 8, base + s * 16);
    }
  };

  f32x4 acc[8][5];
  #pragma unroll
  for (int mi = 0; mi < 8; ++mi)
    #pragma unroll
    for (int ni = 0; ni < 5; ++ni)
      acc[mi][ni] = (f32x4){0.f, 0.f, 0.f, 0.f};

  // ---- prologue (r9): A(0), B(0), A(1) issued; keep A(1) in flight ----
  stageA(0, 0);
  stageB(0, 0);
  stageA(1, 1);
  asm volatile("s_waitcnt vmcnt(4)" ::: "memory");   // drain A(0),B(0); keep A(1)
  __builtin_amdgcn_s_barrier();
  __builtin_amdgcn_sched_barrier(0);

  // ---- main loop: 25 steps x 4 phase-locked sub-phases ----
  for (int t = 0; t < NSTEP; ++t) {
    const f32x4* Af = (const f32x4*)((char*)lds + (t % 3) * ABYTES);
    const u16*   Bb = (const u16*)((char*)lds + BBASE + (t & 1) * BBYTES);
    bf16x8 bfr[5];

    #pragma unroll
    for (int p = 0; p < 4; ++p) {
      // -- read section: this phase's A fragment pair (+ B frags / staging) --
      f32x4 ra0[2], ra1[2];
      #pragma unroll
      for (int j = 0; j < 2; ++j) {
        int R = wm * 128 + (2 * p + j) * 16 + l16;
        ra0[j] = Af[R * 8 + ((2 * lhi)     ^ (R & 7))];
        ra1[j] = Af[R * 8 + ((2 * lhi + 1) ^ (R & 7))];
      }
      if (p == 0) {
        #pragma unroll
        for (int ni = 0; ni < 5; ++ni) {
          int n = wvn + ni * 16 + l16;
          bfr[ni] = *reinterpret_cast<const bf16x8*>(Bb + (n * 4 + (lhi ^ (n & 3))) * 8);
        }
        stageB((t + 1) & 1, t + 1);    // 3 gll (dummy at t=24)
      }
      if (p == 1)
        stageA((t + 2) % 3, t + 2);    // 4 gll (dummies at tail)
      __builtin_amdgcn_sched_barrier(0);
      __builtin_amdgcn_s_barrier();
      asm volatile("s_waitcnt lgkmcnt(0)" ::: "memory");
      __builtin_amdgcn_sched_barrier(0);
      // -- MFMA cluster (register-only) --
      __builtin_amdgcn_s_setprio(1);
      #pragma unroll
      for (int j = 0; j < 2; ++j) {
        u32x4 amu = { pk2(ra0[j][0], ra0[j][1]), pk2(ra0[j][2], ra0[j][3]),
                      pk2(ra1[j][0], ra1[j][1]), pk2(ra1[j][2], ra1[j][3]) };
        bf16x8 am = __builtin_bit_cast(bf16x8, amu);
        #pragma unroll
        for (int ni = 0; ni < 5; ++ni)
          acc[2 * p + j][ni] =
              __builtin_amdgcn_mfma_f32_16x16x32_bf16(am, bfr[ni], acc[2 * p + j][ni], 0, 0, 0);
      }
      __builtin_amdgcn_s_setprio(0);
      __builtin_amdgcn_sched_barrier(0);
      if (p == 3)   // once per step: drain A(t+1),B(t+1); keep A(t+2) in flight
        asm volatile("s_waitcnt vmcnt(4)" ::: "memory");
      __builtin_amdgcn_s_barrier();
      __builtin_amdgcn_sched_barrier(0);
    }
  }
  __syncthreads();    // full drain (incl. dummy stages) before LDS overlay

  // ---- epilogue: h1 = relu(acc + b1); out = h1 @ w2 + b2, 4 passes of 64 rows ----
  u16* H1  = lds;                  // [64][328] = 20992 u16
  u16* W2T = lds + 20992;          // [16][328] = 5248 u16 (52480 B <= 139264)

  for (int i = tid; i < 16 * NP; i += NTHR) {
    int d = i / NP, n = i - (i / NP) * NP;
    float v = (d < DDIM && n < NDIM) ? w2[n * DDIM + d] : 0.f;
    W2T[d * H1STR + n] = f2bf(v);
  }
  float biasv[5];
  #pragma unroll
  for (int ni = 0; ni < 5; ++ni) {
    int col = wvn + ni * 16 + l16;
    biasv[ni] = (col < NDIM) ? b1[col] : 0.f;
  }

  #pragma unroll
  for (int p = 0; p < 4; ++p) {
    if (wm == (p >> 1)) {
      #pragma unroll
      for (int mj = 0; mj < 4; ++mj) {
        int mi = (p & 1) * 4 + mj;
        #pragma unroll
        for (int ni = 0; ni < 5; ++ni) {
          int col = wvn + ni * 16 + l16;
          int rb  = mj * 16 + lhi * 4;
          #pragma unroll
          for (int r = 0; r < 4; ++r) {
            float h = acc[mi][ni][r] + biasv[ni];
            H1[(rb + r) * H1STR + col] = f2bf(fmaxf(h, 0.f));
          }
        }
      }
    }
    __syncthreads();               // H1 (and W2T on p==0) visible
    if (wv < 4) {
      f32x4 a2c = (f32x4){0.f, 0.f, 0.f, 0.f};
      #pragma unroll
      for (int ks = 0; ks < NP / 32; ++ks) {
        bf16x8 a2 = *reinterpret_cast<const bf16x8*>(
            H1 + (wv * 16 + l16) * H1STR + ks * 32 + lhi * 8);
        bf16x8 bw = *reinterpret_cast<const bf16x8*>(
            W2T + l16 * H1STR + ks * 32 + lhi * 8);
        a2c = __builtin_amdgcn_mfma_f32_16x16x32_bf16(a2, bw, a2c, 0, 0, 0);
      }
      if (l16 < DDIM) {
        float bb = b2[l16];
        #pragma unroll
        for (int r = 0; r < 4; ++r) {
          int row = bm + p * 64 + wv * 16 + lhi * 4 + r;
          out[(size_t)row * DDIM + l16] = a2c[r] + bb;
        }
      }
    }
    __syncthreads();               // before next pass overwrites H1
  }
}

extern "C" void kernel_launch(void* const* d_in, const int* in_sizes, int n_in,
                              void* d_out, int out_size, void* d_ws, size_t ws_size,
                              hipStream_t stream) {
  const float* x  = (const float*)d_in[0];
  const float* cw = (const float*)d_in[1];
  const float* w1 = (const float*)d_in[2];
  const float* b1 = (const float*)d_in[3];
  const float* w2 = (const float*)d_in[4];
  const float* b2 = (const float*)d_in[5];
  float* out = (float*)d_out;
  u16* weff = (u16*)d_ws;   // 320*800*2 = 512000 bytes

  hipLaunchKernelGGL(build_weff, dim3((NP * KP + 255) / 256), dim3(256), 0, stream,
                     cw, w1, weff);
  hipLaunchKernelGGL(fused_mlp, dim3(NROW / BM), dim3(NTHR), 0, stream,
                     x, b1, w2, b2, weff, out);
}